// Round 1
// baseline (139.749 us; speedup 1.0000x reference)
//
#include <hip/hip_runtime.h>

typedef short s16x8 __attribute__((ext_vector_type(8)));
typedef float f32x4_t __attribute__((ext_vector_type(4)));

#define VOL 98
#define VPAD 112
#define CH 128

// ---------------- LDS layout ----------------
struct Smem {
  unsigned short xn[VPAD * CH];     // 112x128 bf16, stride 256B; reused as O buffer
  unsigned short qk[VPAD * 256];    // cols 0..127 = q (scaled), 128..255 = k; stride 512B
  unsigned short vt[CH * CH];       // V^T: [d 0..127][token 0..127]; stride 256B
  unsigned short pbuf[8][16 * CH];  // per-wave P tile [16][128]; stride 256B
  int cat[VPAD];
  int gidx[VPAD];
};

__device__ __forceinline__ unsigned short f2bf(float f) {
  unsigned int u = __float_as_uint(f);
  unsigned int r = u + 0x7FFFu + ((u >> 16) & 1u);
  return (unsigned short)(r >> 16);
}

// swizzled LDS fragment read: 16B at [row][colEl], byte ^= (row&7)<<4
__device__ __forceinline__ s16x8 ldsFrag(const unsigned short* buf, int row, int colEl, int strideB) {
  int off = row * strideB + colEl * 2;
  off ^= (row & 7) << 4;
  return *(const s16x8*)((const char*)buf + off);
}
__device__ __forceinline__ void ldsW16(unsigned short* buf, int row, int colEl, int strideB, unsigned short v) {
  int off = row * strideB + colEl * 2;
  off ^= (row & 7) << 4;
  *(unsigned short*)((char*)buf + off) = v;
}
__device__ __forceinline__ void ldsW32(unsigned short* buf, int row, int colEl, int strideB, unsigned int v) {
  int off = row * strideB + colEl * 2;
  off ^= (row & 7) << 4;
  *(unsigned int*)((char*)buf + off) = v;
}

// ---------------- weight prepack: fp32 -> bf16 B-fragments ----------------
// frag layout: dst[((ct*4+ks)*64 + lane)*8 + j] = W[(ks*32 + (lane>>4)*8 + j)][ct*16 + (lane&15)]
__global__ void prepack_weights(const float* __restrict__ wqkv,
                                const float* __restrict__ wproj,
                                unsigned short* __restrict__ dst) {
  int lane = threadIdx.x;
  int blk = blockIdx.x;
  if (blk < 96) {  // w_qkv: 24 col-tiles x 4 ksteps
    int ct = blk >> 2, ks = blk & 3;
    int r0 = ks * 32 + ((lane >> 4) << 3);
    int col = ct * 16 + (lane & 15);
    unsigned short* d = dst + (((size_t)(ct * 4 + ks) * 64 + lane) * 8);
#pragma unroll
    for (int j = 0; j < 8; ++j) d[j] = f2bf(wqkv[(size_t)(r0 + j) * 384 + col]);
  } else {  // w_proj: 8 col-tiles x 4 ksteps
    int bb = blk - 96;
    int ct = bb >> 2, ks = bb & 3;
    int r0 = ks * 32 + ((lane >> 4) << 3);
    int col = ct * 16 + (lane & 15);
    unsigned short* d = dst + 49152 + (((size_t)(ct * 4 + ks) * 64 + lane) * 8);
#pragma unroll
    for (int j = 0; j < 8; ++j) d[j] = f2bf(wproj[(size_t)(r0 + j) * 128 + col]);
  }
}

// ---------------- fused kernel: one block per cuboid ----------------
__global__ __launch_bounds__(512, 2) void fused_cuboid_attn(
    const float* __restrict__ x, const float* __restrict__ gamma,
    const float* __restrict__ beta, const float* __restrict__ bproj,
    const unsigned short* __restrict__ wfrag, float* __restrict__ out) {
  __shared__ Smem s;
  const int tid = threadIdx.x;
  const int lane = tid & 63;
  const int wave = tid >> 6;
  const int l15 = lane & 15;
  const int lg = lane >> 4;  // 0..3
  const int bid = blockIdx.x;
  const int b = bid >> 9;
  const int n = bid & 511;
  const int nt = n >> 6, nh = (n >> 3) & 7, nw = n & 7;

  // phase 0: zero all LDS
  {
    int4* p = (int4*)&s;
    const int tot = sizeof(Smem) / 16;
    for (int i = tid; i < tot; i += 512) p[i] = make_int4(0, 0, 0, 0);
  }
  __syncthreads();

  // phase 1: LayerNorm (one token per wave iteration), + cat/gidx tables
  {
    if (tid >= VOL && tid < VPAD) s.cat[tid] = -1;
    const float2 g2 = *(const float2*)(gamma + lane * 2);
    const float2 be2 = *(const float2*)(beta + lane * 2);
    for (int i = wave; i < VOL; i += 8) {
      int dt = i / 49, rem = i - dt * 49;
      int dh = rem / 7, dw = rem - dh * 7;
      int t = nt * 2 + dt, h = nh * 7 + dh, w = nw * 7 + dw;
      int ts = (t + 1) & 15;
      int hs = h + 3; if (hs >= 56) hs -= 56;
      int ws2 = w + 3; if (ws2 >= 56) ws2 -= 56;
      int gi = ((b * 16 + ts) * 56 + hs) * 56 + ws2;
      float2 v = *(const float2*)(x + (size_t)gi * CH + lane * 2);
      float sum = v.x + v.y;
      float ssq = v.x * v.x + v.y * v.y;
#pragma unroll
      for (int m = 1; m < 64; m <<= 1) {
        sum += __shfl_xor(sum, m);
        ssq += __shfl_xor(ssq, m);
      }
      float mean = sum * (1.0f / 128.0f);
      float var = ssq * (1.0f / 128.0f) - mean * mean;
      float rstd = rsqrtf(var + 1e-5f);
      float y0 = (v.x - mean) * rstd * g2.x + be2.x;
      float y1 = (v.y - mean) * rstd * g2.y + be2.y;
      ldsW32(s.xn, i, lane * 2, 256, (unsigned int)f2bf(y0) | ((unsigned int)f2bf(y1) << 16));
      if (lane == 0) {
        int tc = (t < 14) ? 0 : ((t < 15) ? 1 : 2);
        int hc = (h < 49) ? 0 : ((h < 53) ? 1 : 2);
        int wc = (w < 49) ? 0 : ((w < 53) ? 1 : 2);
        s.cat[i] = tc * 9 + hc * 3 + wc;
        s.gidx[i] = gi;
      }
    }
  }
  __syncthreads();

  // phase 2: QKV GEMM  (112x128 @ 128x384), 168 output tiles of 16x16
  {
    for (int tile = wave; tile < 168; tile += 8) {
      int it = tile / 24, ct = tile - it * 24;
      f32x4_t acc = {0.f, 0.f, 0.f, 0.f};
#pragma unroll
      for (int ks = 0; ks < 4; ++ks) {
        s16x8 a = ldsFrag(s.xn, it * 16 + l15, ks * 32 + lg * 8, 256);
        s16x8 bf = *(const s16x8*)(wfrag + (((size_t)(ct * 4 + ks) * 64 + lane) * 8));
        acc = __builtin_amdgcn_mfma_f32_16x16x32_bf16(a, bf, acc, 0, 0, 0);
      }
      const int cbase = ct * 16 + l15;
      const int rbase = it * 16 + (lg << 2);
#pragma unroll
      for (int r = 0; r < 4; ++r) {
        float v = acc[r];
        int row = rbase + r;
        if (ct < 16) {                       // q (scaled) / k -> qk buffer
          if (ct < 8) v *= 0.17677669529663687f;
          ldsW16(s.qk, row, cbase, 512, f2bf(v));
        } else {                             // v -> V^T buffer
          ldsW16(s.vt, cbase - 256, row, 256, f2bf(v));
        }
      }
    }
  }
  __syncthreads();

  // phase 3: attention, unit = (head, query row-tile), 28 units
  {
    unsigned short* pb = s.pbuf[wave];
    for (int u = wave; u < 28; u += 8) {
      int hh = u / 7, it = u - hh * 7;
      s16x8 qa = ldsFrag(s.qk, it * 16 + l15, hh * 32 + lg * 8, 512);
      f32x4_t sc[7];
#pragma unroll
      for (int jt = 0; jt < 7; ++jt) {
        s16x8 kb = ldsFrag(s.qk, jt * 16 + l15, 128 + hh * 32 + lg * 8, 512);
        f32x4_t z = {0.f, 0.f, 0.f, 0.f};
        sc[jt] = __builtin_amdgcn_mfma_f32_16x16x32_bf16(qa, kb, z, 0, 0, 0);
      }
      // mask (cat mismatch -> -1e30)
      int qcat[4];
#pragma unroll
      for (int r = 0; r < 4; ++r) qcat[r] = s.cat[it * 16 + (lg << 2) + r];
#pragma unroll
      for (int jt = 0; jt < 7; ++jt) {
        int ccat = s.cat[jt * 16 + l15];
#pragma unroll
        for (int r = 0; r < 4; ++r)
          if (ccat != qcat[r]) sc[jt][r] = -1e30f;
      }
      // softmax per row (rows live in 16-lane groups, cols across lanes)
      float rinv[4];
#pragma unroll
      for (int r = 0; r < 4; ++r) {
        float m = sc[0][r];
#pragma unroll
        for (int jt = 1; jt < 7; ++jt) m = fmaxf(m, sc[jt][r]);
#pragma unroll
        for (int d = 1; d < 16; d <<= 1) m = fmaxf(m, __shfl_xor(m, d));
        float ssum = 0.f;
#pragma unroll
        for (int jt = 0; jt < 7; ++jt) {
          float p = exp2f((sc[jt][r] - m) * 1.4426950408889634f);
          sc[jt][r] = p;
          ssum += p;
        }
#pragma unroll
        for (int d = 1; d < 16; d <<= 1) ssum += __shfl_xor(ssum, d);
        rinv[r] = 1.0f / ssum;
      }
      // write P (bf16) to per-wave buffer
#pragma unroll
      for (int jt = 0; jt < 7; ++jt) {
#pragma unroll
        for (int r = 0; r < 4; ++r) {
          ldsW16(pb, (lg << 2) + r, jt * 16 + l15, 256, f2bf(sc[jt][r] * rinv[r]));
        }
      }
      // PV: O(16x32) = P(16x128) @ V(128x32)
#pragma unroll
      for (int dt2 = 0; dt2 < 2; ++dt2) {
        f32x4_t o = {0.f, 0.f, 0.f, 0.f};
#pragma unroll
        for (int ks = 0; ks < 4; ++ks) {
          s16x8 pa = ldsFrag(pb, l15, ks * 32 + lg * 8, 256);
          s16x8 vb = ldsFrag(s.vt, hh * 32 + dt2 * 16 + l15, ks * 32 + lg * 8, 256);
          o = __builtin_amdgcn_mfma_f32_16x16x32_bf16(pa, vb, o, 0, 0, 0);
        }
#pragma unroll
        for (int r = 0; r < 4; ++r) {
          ldsW16(s.xn, it * 16 + (lg << 2) + r, hh * 32 + dt2 * 16 + l15, 256, f2bf(o[r]));
        }
      }
    }
  }
  __syncthreads();

  // phase 4: proj GEMM (112x128 @ 128x128) + bias + scattered store
  {
    const unsigned short* wp = wfrag + 49152;
    for (int tile = wave; tile < 56; tile += 8) {
      int it = tile >> 3, ct = tile & 7;
      f32x4_t acc = {0.f, 0.f, 0.f, 0.f};
#pragma unroll
      for (int ks = 0; ks < 4; ++ks) {
        s16x8 a = ldsFrag(s.xn, it * 16 + l15, ks * 32 + lg * 8, 256);
        s16x8 bf = *(const s16x8*)(wp + (((size_t)(ct * 4 + ks) * 64 + lane) * 8));
        acc = __builtin_amdgcn_mfma_f32_16x16x32_bf16(a, bf, acc, 0, 0, 0);
      }
      int c = ct * 16 + l15;
      float bias = bproj[c];
#pragma unroll
      for (int r = 0; r < 4; ++r) {
        int row = it * 16 + (lg << 2) + r;
        if (row < VOL) {
          out[(size_t)s.gidx[row] * CH + c] = acc[r] + bias;
        }
      }
    }
  }
}

extern "C" void kernel_launch(void* const* d_in, const int* in_sizes, int n_in,
                              void* d_out, int out_size, void* d_ws, size_t ws_size,
                              hipStream_t stream) {
  const float* x = (const float*)d_in[0];
  const float* gamma = (const float*)d_in[1];
  const float* beta = (const float*)d_in[2];
  const float* wqkv = (const float*)d_in[3];
  const float* wproj = (const float*)d_in[4];
  const float* bproj = (const float*)d_in[5];
  float* out = (float*)d_out;
  unsigned short* wsf = (unsigned short*)d_ws;
  (void)in_sizes; (void)n_in; (void)out_size; (void)ws_size;

  prepack_weights<<<128, 64, 0, stream>>>(wqkv, wproj, wsf);
  fused_cuboid_attn<<<1024, 512, 0, stream>>>(x, gamma, beta, bproj, wsf, out);
}

// Round 2
// 97.010 us; speedup vs baseline: 1.4406x; 1.4406x over previous
//
#include <hip/hip_runtime.h>

typedef short s16x8 __attribute__((ext_vector_type(8)));
typedef float f32x4_t __attribute__((ext_vector_type(4)));

#define VOL 98
#define VPAD 112
#define CH 128
#define NW 14
#define NT (NW * 64)

struct Smem {
  unsigned short xn[VPAD * CH];     // 28672 B [token][c], stride 256B; reused as O
  unsigned short qk[VPAD * 256];    // 57344 B [token][c]: c<128 Q(scaled), c>=128 K; stride 512B
  unsigned short vt[CH * CH];       // 32768 B V^T [d][token]; stride 256B
  unsigned short pst[NW][16 * 32];  // 14336 B per-wave P staging [q16][j32]; stride 64B
  unsigned int catmask[28 * 4];     // bit j of catmask[c*4..] => token j has category c
  int cat[VPAD];
  int gidx[VPAD];
};

__device__ __forceinline__ unsigned short f2bf(float f) {
  unsigned int u = __float_as_uint(f);
  unsigned int r = u + 0x7FFFu + ((u >> 16) & 1u);
  return (unsigned short)(r >> 16);
}
__device__ __forceinline__ unsigned int pk2(float a, float b) {
  return (unsigned int)f2bf(a) | ((unsigned int)f2bf(b) << 16);
}
__device__ __forceinline__ int swz(int row, int colEl, int strideB) {
  return (row * strideB + colEl * 2) ^ ((row & 7) << 4);
}
__device__ __forceinline__ s16x8 ldsRd(const unsigned short* buf, int row, int colEl, int strideB) {
  return *(const s16x8*)((const char*)buf + swz(row, colEl, strideB));
}
__device__ __forceinline__ void ldsWr64(unsigned short* buf, int row, int colEl, int strideB,
                                        unsigned int lo, unsigned int hi) {
  unsigned long long v = (unsigned long long)lo | ((unsigned long long)hi << 32);
  *(unsigned long long*)((char*)buf + swz(row, colEl, strideB)) = v;
}
__device__ __forceinline__ void ldsWr128(unsigned short* buf, int row, int colEl, int strideB, uint4 v) {
  *(uint4*)((char*)buf + swz(row, colEl, strideB)) = v;
}

// ---------------- weight prepack: fp32 -> bf16 fragments (A/B symmetric layout) ----------------
__global__ void prepack_weights(const float* __restrict__ wqkv,
                                const float* __restrict__ wproj,
                                unsigned short* __restrict__ dst) {
  int lane = threadIdx.x;
  int blk = blockIdx.x;
  if (blk < 96) {
    int ct = blk >> 2, ks = blk & 3;
    int r0 = ks * 32 + ((lane >> 4) << 3);
    int col = ct * 16 + (lane & 15);
    unsigned short* d = dst + (((size_t)(ct * 4 + ks) * 64 + lane) * 8);
#pragma unroll
    for (int j = 0; j < 8; ++j) d[j] = f2bf(wqkv[(size_t)(r0 + j) * 384 + col]);
  } else {
    int bb = blk - 96;
    int ct = bb >> 2, ks = bb & 3;
    int r0 = ks * 32 + ((lane >> 4) << 3);
    int col = ct * 16 + (lane & 15);
    unsigned short* d = dst + 49152 + (((size_t)(ct * 4 + ks) * 64 + lane) * 8);
#pragma unroll
    for (int j = 0; j < 8; ++j) d[j] = f2bf(wproj[(size_t)(r0 + j) * 128 + col]);
  }
}

// ---------------- fused kernel: one block per cuboid ----------------
__global__ __launch_bounds__(NT, 4) void fused_cuboid_attn(
    const float* __restrict__ x, const float* __restrict__ gamma,
    const float* __restrict__ beta, const float* __restrict__ bproj,
    const unsigned short* __restrict__ wfrag, float* __restrict__ out) {
  __shared__ Smem s;
  const int tid = threadIdx.x;
  const int lane = tid & 63;
  const int wave = tid >> 6;
  const int l15 = lane & 15;
  const int lg = lane >> 4;
  const int lg4 = lg * 4;
  const int lg8 = lg * 8;
  const int bid = blockIdx.x;
  const int b = bid >> 9;
  const int n = bid & 511;
  const int nt = n >> 6, nh = (n >> 3) & 7, nw = n & 7;

  // phase 0: zero xn+qk+vt (contiguous 118784 B) + catmask; pad cats
  {
    uint4* p = (uint4*)&s;
    uint4 z = make_uint4(0, 0, 0, 0);
    for (int i = tid; i < 118784 / 16; i += NT) p[i] = z;
    if (tid < 112) s.catmask[tid] = 0;
    if (tid >= VOL && tid < VPAD) s.cat[tid] = 0;
  }
  __syncthreads();

  // phase 1: LayerNorm, one token per 16-lane group (8 ch/lane), + tables
  {
    const int grp = tid >> 4;
    const int l = tid & 15;
    const float4 g0 = *(const float4*)(gamma + l * 8);
    const float4 g1 = *(const float4*)(gamma + l * 8 + 4);
    const float4 be0 = *(const float4*)(beta + l * 8);
    const float4 be1 = *(const float4*)(beta + l * 8 + 4);
    for (int i = grp; i < VOL; i += NT / 16) {
      int dt = (i >= 49) ? 1 : 0;
      int rem = i - dt * 49;
      int dh = (rem * 37) >> 8;
      int dw = rem - dh * 7;
      int t = nt * 2 + dt, h = nh * 7 + dh, w = nw * 7 + dw;
      int ts = (t + 1) & 15;
      int hs = h + 3; if (hs >= 56) hs -= 56;
      int ws2 = w + 3; if (ws2 >= 56) ws2 -= 56;
      int gi = ((b * 16 + ts) * 56 + hs) * 56 + ws2;
      const float* xp = x + (size_t)gi * CH + l * 8;
      float4 v0 = *(const float4*)(xp);
      float4 v1 = *(const float4*)(xp + 4);
      float sum = v0.x + v0.y + v0.z + v0.w + v1.x + v1.y + v1.z + v1.w;
      float ssq = v0.x * v0.x + v0.y * v0.y + v0.z * v0.z + v0.w * v0.w +
                  v1.x * v1.x + v1.y * v1.y + v1.z * v1.z + v1.w * v1.w;
#pragma unroll
      for (int d = 1; d < 16; d <<= 1) {
        sum += __shfl_xor(sum, d);
        ssq += __shfl_xor(ssq, d);
      }
      float mean = sum * (1.0f / 128.0f);
      float var = ssq * (1.0f / 128.0f) - mean * mean;
      float rstd = rsqrtf(var + 1e-5f);
      uint4 pkv;
      pkv.x = pk2((v0.x - mean) * rstd * g0.x + be0.x, (v0.y - mean) * rstd * g0.y + be0.y);
      pkv.y = pk2((v0.z - mean) * rstd * g0.z + be0.z, (v0.w - mean) * rstd * g0.w + be0.w);
      pkv.z = pk2((v1.x - mean) * rstd * g1.x + be1.x, (v1.y - mean) * rstd * g1.y + be1.y);
      pkv.w = pk2((v1.z - mean) * rstd * g1.z + be1.z, (v1.w - mean) * rstd * g1.w + be1.w);
      ldsWr128(s.xn, i, l * 8, 256, pkv);
      if (l == 0) {
        int tc = (t < 14) ? 0 : ((t < 15) ? 1 : 2);
        int hc = (h < 49) ? 0 : ((h < 53) ? 1 : 2);
        int wc = (w < 49) ? 0 : ((w < 53) ? 1 : 2);
        int c = tc * 9 + hc * 3 + wc;
        s.cat[i] = c;
        s.gidx[i] = gi;
        atomicOr(&s.catmask[c * 4 + (i >> 5)], 1u << (i & 31));
      }
    }
  }
  __syncthreads();

  // phase 2: QKV GEMM. Q/K swapped-operand (lane holds 4 consecutive channels),
  // V normal (lane holds 4 consecutive tokens -> packed V^T row write).
  {
    for (int tile = wave; tile < 168; tile += NW) {
      int it = tile / 24, ct = tile - it * 24;
      const unsigned short* wf = wfrag + ((size_t)ct * 2048 + (size_t)lane * 8);
      s16x8 xf[4], wv[4];
#pragma unroll
      for (int ks = 0; ks < 4; ++ks) {
        xf[ks] = ldsRd(s.xn, it * 16 + l15, ks * 32 + lg8, 256);
        wv[ks] = *(const s16x8*)(wf + ks * 512);
      }
      f32x4_t acc = {0.f, 0.f, 0.f, 0.f};
      if (ct < 16) {
#pragma unroll
        for (int ks = 0; ks < 4; ++ks)
          acc = __builtin_amdgcn_mfma_f32_16x16x32_bf16(wv[ks], xf[ks], acc, 0, 0, 0);
        float scl = (ct < 8) ? 0.17677669529663687f : 1.0f;
        ldsWr64(s.qk, it * 16 + l15, ct * 16 + lg4, 512,
                pk2(acc[0] * scl, acc[1] * scl), pk2(acc[2] * scl, acc[3] * scl));
      } else {
#pragma unroll
        for (int ks = 0; ks < 4; ++ks)
          acc = __builtin_amdgcn_mfma_f32_16x16x32_bf16(xf[ks], wv[ks], acc, 0, 0, 0);
        ldsWr64(s.vt, (ct - 16) * 16 + l15, it * 16 + lg4, 256,
                pk2(acc[0], acc[1]), pk2(acc[2], acc[3]));
      }
    }
  }
  __syncthreads();

  // phase 3: attention. S^T = mfma(K,Q): lane owns query q=l15, keys j=jt*16+lg4+r.
  {
    unsigned short* ps = s.pst[wave];
    for (int u = wave; u < 28; u += NW) {
      int hh = (u * 37) >> 8;       // u/7
      int it = u - hh * 7;
      s16x8 qa = ldsRd(s.qk, it * 16 + l15, hh * 32 + lg8, 512);
      f32x4_t sc[7];
#pragma unroll
      for (int jt = 0; jt < 7; ++jt) {
        s16x8 kb = ldsRd(s.qk, jt * 16 + l15, 128 + hh * 32 + lg8, 512);
        f32x4_t z = {0.f, 0.f, 0.f, 0.f};
        sc[jt] = __builtin_amdgcn_mfma_f32_16x16x32_bf16(kb, qa, z, 0, 0, 0);
      }
      int cq = s.cat[it * 16 + l15];
      cq = (cq < 0) ? 0 : ((cq > 26) ? 26 : cq);
      uint4 mw = *(const uint4*)&s.catmask[cq * 4];
#pragma unroll
      for (int jt = 0; jt < 7; ++jt) {
        unsigned mword = ((jt >> 1) == 0) ? mw.x : ((jt >> 1) == 1) ? mw.y
                        : ((jt >> 1) == 2) ? mw.z : mw.w;
#pragma unroll
        for (int r = 0; r < 4; ++r) {
          unsigned bit = (mword >> ((jt & 1) * 16 + lg4 + r)) & 1u;
          sc[jt][r] = bit ? sc[jt][r] : -1e30f;
        }
      }
      // softmax over j for fixed q: in-lane 28 values + 2-level cross-lg reduce
      float m = sc[0][0];
#pragma unroll
      for (int jt = 0; jt < 7; ++jt)
#pragma unroll
        for (int r = 0; r < 4; ++r) m = fmaxf(m, sc[jt][r]);
      m = fmaxf(m, __shfl_xor(m, 16));
      m = fmaxf(m, __shfl_xor(m, 32));
      float ssum = 0.f;
#pragma unroll
      for (int jt = 0; jt < 7; ++jt)
#pragma unroll
        for (int r = 0; r < 4; ++r) {
          float p = exp2f((sc[jt][r] - m) * 1.4426950408889634f);
          sc[jt][r] = p;
          ssum += p;
        }
      ssum += __shfl_xor(ssum, 16);
      ssum += __shfl_xor(ssum, 32);
      float rinv = 1.0f / ssum;
      // PV fused per 32-key chunk through tiny per-wave staging tile
      f32x4_t o0 = {0.f, 0.f, 0.f, 0.f}, o1 = {0.f, 0.f, 0.f, 0.f};
#pragma unroll
      for (int ks = 0; ks < 4; ++ks) {
        const int jtA = 2 * ks, jtB = 2 * ks + 1;
        ldsWr64(ps, l15, lg4, 64,
                pk2(sc[jtA][0] * rinv, sc[jtA][1] * rinv),
                pk2(sc[jtA][2] * rinv, sc[jtA][3] * rinv));
        unsigned pb0 = 0, pb1 = 0;
        if (jtB < 7) {
          pb0 = pk2(sc[jtB][0] * rinv, sc[jtB][1] * rinv);
          pb1 = pk2(sc[jtB][2] * rinv, sc[jtB][3] * rinv);
        }
        ldsWr64(ps, l15, 16 + lg4, 64, pb0, pb1);
        s16x8 pa = ldsRd(ps, l15, lg8, 64);
        s16x8 v0 = ldsRd(s.vt, hh * 32 + l15, ks * 32 + lg8, 256);
        s16x8 v1 = ldsRd(s.vt, hh * 32 + 16 + l15, ks * 32 + lg8, 256);
        o0 = __builtin_amdgcn_mfma_f32_16x16x32_bf16(v0, pa, o0, 0, 0, 0);
        o1 = __builtin_amdgcn_mfma_f32_16x16x32_bf16(v1, pa, o1, 0, 0, 0);
      }
      // O^T: lane holds 4 consecutive d for q=l15 -> packed writes into xn
      ldsWr64(s.xn, it * 16 + l15, hh * 32 + lg4, 256, pk2(o0[0], o0[1]), pk2(o0[2], o0[3]));
      ldsWr64(s.xn, it * 16 + l15, hh * 32 + 16 + lg4, 256, pk2(o1[0], o1[1]), pk2(o1[2], o1[3]));
    }
  }
  __syncthreads();

  // phase 4: proj GEMM (swapped: lane holds 4 consecutive channels) + bias + float4 store
  {
    const unsigned short* wp = wfrag + 49152;
    for (int tile = wave; tile < 56; tile += NW) {
      int it = tile >> 3, ct = tile & 7;
      const unsigned short* wf = wp + ((size_t)ct * 2048 + (size_t)lane * 8);
      f32x4_t acc = {0.f, 0.f, 0.f, 0.f};
#pragma unroll
      for (int ks = 0; ks < 4; ++ks) {
        s16x8 of = ldsRd(s.xn, it * 16 + l15, ks * 32 + lg8, 256);
        s16x8 wv = *(const s16x8*)(wf + ks * 512);
        acc = __builtin_amdgcn_mfma_f32_16x16x32_bf16(wv, of, acc, 0, 0, 0);
      }
      int row = it * 16 + l15;
      if (row < VOL) {
        float4 b4 = *(const float4*)(bproj + ct * 16 + lg4);
        float4 res;
        res.x = acc[0] + b4.x;
        res.y = acc[1] + b4.y;
        res.z = acc[2] + b4.z;
        res.w = acc[3] + b4.w;
        *(float4*)(out + (size_t)s.gidx[row] * CH + ct * 16 + lg4) = res;
      }
    }
  }
}

extern "C" void kernel_launch(void* const* d_in, const int* in_sizes, int n_in,
                              void* d_out, int out_size, void* d_ws, size_t ws_size,
                              hipStream_t stream) {
  const float* x = (const float*)d_in[0];
  const float* gamma = (const float*)d_in[1];
  const float* beta = (const float*)d_in[2];
  const float* wqkv = (const float*)d_in[3];
  const float* wproj = (const float*)d_in[4];
  const float* bproj = (const float*)d_in[5];
  float* out = (float*)d_out;
  unsigned short* wsf = (unsigned short*)d_ws;
  (void)in_sizes; (void)n_in; (void)out_size; (void)ws_size;

  prepack_weights<<<128, 64, 0, stream>>>(wqkv, wproj, wsf);
  fused_cuboid_attn<<<1024, NT, 0, stream>>>(x, gamma, beta, bproj, wsf, out);
}

// Round 5
// 92.758 us; speedup vs baseline: 1.5066x; 1.0458x over previous
//
#include <hip/hip_runtime.h>

typedef short s16x8 __attribute__((ext_vector_type(8)));
typedef float f32x4_t __attribute__((ext_vector_type(4)));

#define VOL 98
#define VPAD 112
#define CH 128
#define NW 14
#define NT (NW * 64)
#define MASKNEG -1e9f

struct Smem {
  unsigned short xn[VPAD * CH];     // 28672 B [token][c] stride 256B; reused as O
  unsigned short qk[VPAD * 256];    // 57344 B [token][c]: c<128 Q(scaled), c>=128 K; stride 512B
  unsigned short vt[CH * CH];       // 32768 B V^T [d][token]; stride 256B
  unsigned short pst[NW][16 * 32];  // 14336 B per-wave P staging [q16][j32]; stride 64B
  float catAddF[27 * 128];          // 13824 B additive mask rows (0/MASKNEG), stride 512B, swz (c&7)<<4
  int cat[VPAD];
  int gidx[VPAD];
};

__device__ __forceinline__ unsigned short f2bf(float f) {
  unsigned int u = __float_as_uint(f);
  unsigned int r = u + 0x7FFFu + ((u >> 16) & 1u);
  return (unsigned short)(r >> 16);
}
__device__ __forceinline__ unsigned int pk2(float a, float b) {
  return (unsigned int)f2bf(a) | ((unsigned int)f2bf(b) << 16);
}
__device__ __forceinline__ int swz(int row, int colEl, int strideB) {
  return (row * strideB + colEl * 2) ^ ((row & 7) << 4);
}
__device__ __forceinline__ s16x8 ldsRd(const unsigned short* buf, int row, int colEl, int strideB) {
  return *(const s16x8*)((const char*)buf + swz(row, colEl, strideB));
}
__device__ __forceinline__ void ldsWr64(unsigned short* buf, int row, int colEl, int strideB,
                                        unsigned int lo, unsigned int hi) {
  unsigned long long v = (unsigned long long)lo | ((unsigned long long)hi << 32);
  *(unsigned long long*)((char*)buf + swz(row, colEl, strideB)) = v;
}
__device__ __forceinline__ void ldsWr128(unsigned short* buf, int row, int colEl, int strideB, uint4 v) {
  *(uint4*)((char*)buf + swz(row, colEl, strideB)) = v;
}

// ---------------- weight prepack: fp32 -> bf16 fragments ----------------
__global__ void prepack_weights(const float* __restrict__ wqkv,
                                const float* __restrict__ wproj,
                                unsigned short* __restrict__ dst) {
  int lane = threadIdx.x;
  int blk = blockIdx.x;
  if (blk < 96) {
    int ct = blk >> 2, ks = blk & 3;
    int r0 = ks * 32 + ((lane >> 4) << 3);
    int col = ct * 16 + (lane & 15);
    unsigned short* d = dst + (((size_t)(ct * 4 + ks) * 64 + lane) * 8);
#pragma unroll
    for (int j = 0; j < 8; ++j) d[j] = f2bf(wqkv[(size_t)(r0 + j) * 384 + col]);
  } else {
    int bb = blk - 96;
    int ct = bb >> 2, ks = bb & 3;
    int r0 = ks * 32 + ((lane >> 4) << 3);
    int col = ct * 16 + (lane & 15);
    unsigned short* d = dst + 49152 + (((size_t)(ct * 4 + ks) * 64 + lane) * 8);
#pragma unroll
    for (int j = 0; j < 8; ++j) d[j] = f2bf(wproj[(size_t)(r0 + j) * 128 + col]);
  }
}

// ---------------- fused kernel: one block per cuboid ----------------
__global__ __launch_bounds__(NT, 4) void fused_cuboid_attn(
    const float* __restrict__ x, const float* __restrict__ gamma,
    const float* __restrict__ beta, const float* __restrict__ bproj,
    const unsigned short* __restrict__ wfrag, float* __restrict__ out) {
  __shared__ Smem s;
  const int tid = threadIdx.x;
  const int lane = tid & 63;
  const int wave = tid >> 6;
  const int l15 = lane & 15;
  const int lg = lane >> 4;
  const int lg4 = lg * 4;
  const int lg8 = lg * 8;
  const int bid = blockIdx.x;
  const int b = bid >> 9;
  const int n = bid & 511;
  const int nt = n >> 6, nh = (n >> 3) & 7, nw = n & 7;
  const int itw = (wave < 7) ? wave : wave - 7;   // each wave owns row-tile itw
  const int half = (wave < 7) ? 0 : 1;

  // phase 0: zero the ENTIRE Smem (R1-proven). No read of uninitialized LDS
  // anywhere afterward.
  {
    uint4 z = make_uint4(0, 0, 0, 0);
    uint4* p = (uint4*)&s;
    for (int i = tid; i < (int)(sizeof(Smem) / 16); i += NT) p[i] = z;
  }
  __syncthreads();

  // phase 1: LayerNorm, one token per 16-lane group (8 ch/lane), + tables
  {
    if (tid < VPAD - VOL) s.cat[VOL + tid] = -1;  // pad cats (after zeroing barrier)
    const int grp = tid >> 4;
    const int l = tid & 15;
    const float4 g0 = *(const float4*)(gamma + l * 8);
    const float4 g1 = *(const float4*)(gamma + l * 8 + 4);
    const float4 be0 = *(const float4*)(beta + l * 8);
    const float4 be1 = *(const float4*)(beta + l * 8 + 4);
    for (int i = grp; i < VOL; i += NT / 16) {
      int dt = (i >= 49) ? 1 : 0;
      int rem = i - dt * 49;
      int dh = (rem * 37) >> 8;
      int dw = rem - dh * 7;
      int t = nt * 2 + dt, h = nh * 7 + dh, w = nw * 7 + dw;
      int ts = (t + 1) & 15;
      int hs = h + 3; if (hs >= 56) hs -= 56;
      int ws2 = w + 3; if (ws2 >= 56) ws2 -= 56;
      int gi = ((b * 16 + ts) * 56 + hs) * 56 + ws2;
      const float* xp = x + (size_t)gi * CH + l * 8;
      float4 v0 = *(const float4*)(xp);
      float4 v1 = *(const float4*)(xp + 4);
      float sum = v0.x + v0.y + v0.z + v0.w + v1.x + v1.y + v1.z + v1.w;
      float ssq = v0.x * v0.x + v0.y * v0.y + v0.z * v0.z + v0.w * v0.w +
                  v1.x * v1.x + v1.y * v1.y + v1.z * v1.z + v1.w * v1.w;
#pragma unroll
      for (int d = 1; d < 16; d <<= 1) {
        sum += __shfl_xor(sum, d);
        ssq += __shfl_xor(ssq, d);
      }
      float mean = sum * (1.0f / 128.0f);
      float var = ssq * (1.0f / 128.0f) - mean * mean;
      float rstd = rsqrtf(var + 1e-5f);
      uint4 pkv;
      pkv.x = pk2((v0.x - mean) * rstd * g0.x + be0.x, (v0.y - mean) * rstd * g0.y + be0.y);
      pkv.y = pk2((v0.z - mean) * rstd * g0.z + be0.z, (v0.w - mean) * rstd * g0.w + be0.w);
      pkv.z = pk2((v1.x - mean) * rstd * g1.x + be1.x, (v1.y - mean) * rstd * g1.y + be1.y);
      pkv.w = pk2((v1.z - mean) * rstd * g1.z + be1.z, (v1.w - mean) * rstd * g1.w + be1.w);
      ldsWr128(s.xn, i, l * 8, 256, pkv);
      if (l == 0) {
        int tc = (t < 14) ? 0 : ((t < 15) ? 1 : 2);
        int hc = (h < 49) ? 0 : ((h < 53) ? 1 : 2);
        int wc = (w < 49) ? 0 : ((w < 53) ? 1 : 2);
        s.cat[i] = tc * 9 + hc * 3 + wc;
        s.gidx[i] = gi;
      }
    }
  }
  __syncthreads();

  // phase 2a: build additive-mask table (27 cats x 112 j, f32, swizzled)
  if (tid < 27 * 28) {
    int c = (tid * 2341) >> 16;   // tid/28 exact for tid<756
    int j = (tid - c * 28) * 4;
    float4 mv;
    mv.x = (s.cat[j + 0] == c) ? 0.f : MASKNEG;
    mv.y = (s.cat[j + 1] == c) ? 0.f : MASKNEG;
    mv.z = (s.cat[j + 2] == c) ? 0.f : MASKNEG;
    mv.w = (s.cat[j + 3] == c) ? 0.f : MASKNEG;
    *(float4*)((char*)s.catAddF + ((c * 512 + j * 4) ^ ((c & 7) << 4))) = mv;
  }

  // phase 2b: QKV GEMM. Wave owns it=itw, loops 12 ct tiles reusing A-frags.
  // Q/K swapped-operand (lane: 4 consecutive channels); V normal (4 consecutive tokens).
  {
    const float QSCALE = (float)(0.17677669529663687 * 1.4426950408889634);  // hd^-0.5 * log2e
    s16x8 xf[4];
#pragma unroll
    for (int ks = 0; ks < 4; ++ks) xf[ks] = ldsRd(s.xn, itw * 16 + l15, ks * 32 + lg8, 256);
#pragma unroll 4
    for (int cc = 0; cc < 12; ++cc) {
      int ct = half * 12 + cc;
      const unsigned short* wf = wfrag + ((size_t)ct * 2048 + (size_t)lane * 8);
      s16x8 wv[4];
#pragma unroll
      for (int ks = 0; ks < 4; ++ks) wv[ks] = *(const s16x8*)(wf + ks * 512);
      f32x4_t acc = {0.f, 0.f, 0.f, 0.f};
      if (ct < 16) {
#pragma unroll
        for (int ks = 0; ks < 4; ++ks)
          acc = __builtin_amdgcn_mfma_f32_16x16x32_bf16(wv[ks], xf[ks], acc, 0, 0, 0);
        float scl = (ct < 8) ? QSCALE : 1.0f;
        ldsWr64(s.qk, itw * 16 + l15, ct * 16 + lg4, 512,
                pk2(acc[0] * scl, acc[1] * scl), pk2(acc[2] * scl, acc[3] * scl));
      } else {
#pragma unroll
        for (int ks = 0; ks < 4; ++ks)
          acc = __builtin_amdgcn_mfma_f32_16x16x32_bf16(xf[ks], wv[ks], acc, 0, 0, 0);
        ldsWr64(s.vt, (ct - 16) * 16 + l15, itw * 16 + lg4, 256,
                pk2(acc[0], acc[1]), pk2(acc[2], acc[3]));
      }
    }
  }
  __syncthreads();

  // phase 3: attention. S^T = mfma(K, Q, C=mask). Lane owns query q, keys j=jt*16+lg4+r.
  {
    unsigned short* ps = s.pst[wave];
    const int q = itw * 16 + l15;
    int cq = s.cat[q]; if (cq < 0) cq = 0;
    const char* mrow = (const char*)s.catAddF + cq * 512;
    const int msw = (cq & 7) << 4;
    f32x4_t cm[7];
#pragma unroll
    for (int jt = 0; jt < 7; ++jt)
      cm[jt] = *(const f32x4_t*)(mrow + (((jt * 16 + lg4) * 4) ^ msw));
#pragma unroll
    for (int k = 0; k < 2; ++k) {
      const int hh = half + 2 * k;   // waves<7: heads {0,2}; waves>=7: heads {1,3}
      s16x8 qa = ldsRd(s.qk, q, hh * 32 + lg8, 512);
      f32x4_t sc[7];
#pragma unroll
      for (int jt = 0; jt < 7; ++jt) {
        s16x8 kb = ldsRd(s.qk, jt * 16 + l15, 128 + hh * 32 + lg8, 512);
        sc[jt] = __builtin_amdgcn_mfma_f32_16x16x32_bf16(kb, qa, cm[jt], 0, 0, 0);
      }
      // softmax over j (log2-domain; scale folded into Q)
      float m = sc[0][0];
#pragma unroll
      for (int jt = 0; jt < 7; ++jt)
#pragma unroll
        for (int r = 0; r < 4; ++r) m = fmaxf(m, sc[jt][r]);
      m = fmaxf(m, __shfl_xor(m, 16));
      m = fmaxf(m, __shfl_xor(m, 32));
      float ssum = 0.f;
#pragma unroll
      for (int jt = 0; jt < 7; ++jt)
#pragma unroll
        for (int r = 0; r < 4; ++r) {
          float p = exp2f(sc[jt][r] - m);
          sc[jt][r] = p;
          ssum += p;
        }
      ssum += __shfl_xor(ssum, 16);
      ssum += __shfl_xor(ssum, 32);
      float rinv = 1.0f / ssum;   // applied at O epilogue
      // PV per 32-key chunk through per-wave staging tile (P unnormalized)
      f32x4_t o0 = {0.f, 0.f, 0.f, 0.f}, o1 = {0.f, 0.f, 0.f, 0.f};
#pragma unroll
      for (int ks = 0; ks < 4; ++ks) {
        const int jtA = 2 * ks, jtB = 2 * ks + 1;
        ldsWr64(ps, l15, lg4, 64, pk2(sc[jtA][0], sc[jtA][1]), pk2(sc[jtA][2], sc[jtA][3]));
        unsigned pb0 = 0, pb1 = 0;
        if (jtB < 7) {
          pb0 = pk2(sc[jtB][0], sc[jtB][1]);
          pb1 = pk2(sc[jtB][2], sc[jtB][3]);
        }
        ldsWr64(ps, l15, 16 + lg4, 64, pb0, pb1);
        // Compiler-level memory fence: pst is written via u64* and read via
        // short8* (distinct TBAA types, no barrier between) — without this the
        // optimizer may hoist the ds_read above the ds_writes.
        asm volatile("" ::: "memory");
        s16x8 pa = ldsRd(ps, l15, lg8, 64);
        s16x8 v0 = ldsRd(s.vt, hh * 32 + l15, ks * 32 + lg8, 256);
        s16x8 v1 = ldsRd(s.vt, hh * 32 + 16 + l15, ks * 32 + lg8, 256);
        o0 = __builtin_amdgcn_mfma_f32_16x16x32_bf16(v0, pa, o0, 0, 0, 0);
        o1 = __builtin_amdgcn_mfma_f32_16x16x32_bf16(v1, pa, o1, 0, 0, 0);
      }
      // O^T into xn: lane holds 4 consecutive d for its q
      ldsWr64(s.xn, q, hh * 32 + lg4, 256,
              pk2(o0[0] * rinv, o0[1] * rinv), pk2(o0[2] * rinv, o0[3] * rinv));
      ldsWr64(s.xn, q, hh * 32 + 16 + lg4, 256,
              pk2(o1[0] * rinv, o1[1] * rinv), pk2(o1[2] * rinv, o1[3] * rinv));
    }
  }
  __syncthreads();

  // phase 4: proj GEMM (swapped; bias via C-operand) + float4 store
  {
    const unsigned short* wp = wfrag + 49152;
    s16x8 of[4];
#pragma unroll
    for (int ks = 0; ks < 4; ++ks) of[ks] = ldsRd(s.xn, itw * 16 + l15, ks * 32 + lg8, 256);
    const int row = itw * 16 + l15;
    const bool valid = row < VOL;
    const size_t gbase = valid ? (size_t)s.gidx[row] * CH : 0;
#pragma unroll
    for (int cc = 0; cc < 4; ++cc) {
      int ct = half * 4 + cc;
      const unsigned short* wf = wp + ((size_t)ct * 2048 + (size_t)lane * 8);
      float4 b4 = *(const float4*)(bproj + ct * 16 + lg4);
      f32x4_t acc = {b4.x, b4.y, b4.z, b4.w};
#pragma unroll
      for (int ks = 0; ks < 4; ++ks) {
        s16x8 wv = *(const s16x8*)(wf + ks * 512);
        acc = __builtin_amdgcn_mfma_f32_16x16x32_bf16(wv, of[ks], acc, 0, 0, 0);
      }
      if (valid) {
        float4 res;
        res.x = acc[0]; res.y = acc[1]; res.z = acc[2]; res.w = acc[3];
        *(float4*)(out + gbase + ct * 16 + lg4) = res;
      }
    }
  }
}

extern "C" void kernel_launch(void* const* d_in, const int* in_sizes, int n_in,
                              void* d_out, int out_size, void* d_ws, size_t ws_size,
                              hipStream_t stream) {
  const float* x = (const float*)d_in[0];
  const float* gamma = (const float*)d_in[1];
  const float* beta = (const float*)d_in[2];
  const float* wqkv = (const float*)d_in[3];
  const float* wproj = (const float*)d_in[4];
  const float* bproj = (const float*)d_in[5];
  float* out = (float*)d_out;
  unsigned short* wsf = (unsigned short*)d_ws;
  (void)in_sizes; (void)n_in; (void)out_size; (void)ws_size;

  prepack_weights<<<128, 64, 0, stream>>>(wqkv, wproj, wsf);
  fused_cuboid_attn<<<1024, NT, 0, stream>>>(x, gamma, beta, bproj, wsf, out);
}

// Round 6
// 79.384 us; speedup vs baseline: 1.7604x; 1.1685x over previous
//
#include <hip/hip_runtime.h>

typedef short s16x8 __attribute__((ext_vector_type(8)));
typedef float f32x4_t __attribute__((ext_vector_type(4)));

#define VOL 98
#define VPAD 112
#define CH 128
#define NWV 7
#define NTH (NWV * 64)
#define MASKNEG -1e9f

struct Smem {
  unsigned short bufA[VPAD * CH];   // 28672 B: xn (LN out) -> K -> O; stride 256B swz
  unsigned short vt[CH * CH];       // 32768 B: V^T [d][token]; stride 256B swz
  unsigned short pst[NWV][512];     // 7168 B: per-wave P staging [q16][j32]; stride 64B swz
  unsigned int catbits[27][4];      // 432 B: bit j of catbits[c] => token j has category c
  int cat[VPAD];
  int gidx[VPAD];
};

__device__ __forceinline__ unsigned short f2bf(float f) {
  unsigned int u = __float_as_uint(f);
  unsigned int r = u + 0x7FFFu + ((u >> 16) & 1u);
  return (unsigned short)(r >> 16);
}
__device__ __forceinline__ unsigned int pk2(float a, float b) {
  return (unsigned int)f2bf(a) | ((unsigned int)f2bf(b) << 16);
}
__device__ __forceinline__ int swz(int row, int colEl, int strideB) {
  return (row * strideB + colEl * 2) ^ ((row & 7) << 4);
}
__device__ __forceinline__ s16x8 ldsRd(const unsigned short* buf, int row, int colEl, int strideB) {
  return *(const s16x8*)((const char*)buf + swz(row, colEl, strideB));
}
__device__ __forceinline__ void ldsWr64(unsigned short* buf, int row, int colEl, int strideB,
                                        unsigned int lo, unsigned int hi) {
  unsigned long long v = (unsigned long long)lo | ((unsigned long long)hi << 32);
  *(unsigned long long*)((char*)buf + swz(row, colEl, strideB)) = v;
}
__device__ __forceinline__ void ldsWr128(unsigned short* buf, int row, int colEl, int strideB, uint4 v) {
  *(uint4*)((char*)buf + swz(row, colEl, strideB)) = v;
}
__device__ __forceinline__ s16x8 u4cast(unsigned a, unsigned b, unsigned c, unsigned d) {
  union { uint4 u; s16x8 v; } cv;
  cv.u = make_uint4(a, b, c, d);
  return cv.v;
}

// ---------------- weight prepack: fp32 -> bf16 fragments ----------------
__global__ void prepack_weights(const float* __restrict__ wqkv,
                                const float* __restrict__ wproj,
                                unsigned short* __restrict__ dst) {
  int lane = threadIdx.x;
  int blk = blockIdx.x;
  if (blk < 96) {
    int ct = blk >> 2, ks = blk & 3;
    int r0 = ks * 32 + ((lane >> 4) << 3);
    int col = ct * 16 + (lane & 15);
    unsigned short* d = dst + (((size_t)(ct * 4 + ks) * 64 + lane) * 8);
#pragma unroll
    for (int j = 0; j < 8; ++j) d[j] = f2bf(wqkv[(size_t)(r0 + j) * 384 + col]);
  } else {
    int bb = blk - 96;
    int ct = bb >> 2, ks = bb & 3;
    int r0 = ks * 32 + ((lane >> 4) << 3);
    int col = ct * 16 + (lane & 15);
    unsigned short* d = dst + 49152 + (((size_t)(ct * 4 + ks) * 64 + lane) * 8);
#pragma unroll
    for (int j = 0; j < 8; ++j) d[j] = f2bf(wproj[(size_t)(r0 + j) * 128 + col]);
  }
}

// ---------------- fused kernel: one block per cuboid, 7 waves ----------------
__global__ __launch_bounds__(NTH, 4) void fused_cuboid_attn(
    const float* __restrict__ x, const float* __restrict__ gamma,
    const float* __restrict__ beta, const float* __restrict__ bproj,
    const unsigned short* __restrict__ wfrag, float* __restrict__ out) {
  __shared__ Smem s;
  const int tid = threadIdx.x;
  const int lane = tid & 63;
  const int itw = tid >> 6;          // wave id == row-tile id (0..6)
  const int l15 = lane & 15;
  const int lg = lane >> 4;
  const int lg4 = lg * 4;
  const int lg8 = lg * 8;
  const int bid = blockIdx.x;
  const int b = bid >> 9;
  const int n = bid & 511;
  const int nt = n >> 6, nh = (n >> 3) & 7, nw = n & 7;

  // phase 0: zero vt (fully: swizzle scatters unwritten token-cols 112..127),
  // bufA pad rows 98..111 (-> zero K pads via GEMM), catbits, cat pads.
  {
    uint4 z = make_uint4(0, 0, 0, 0);
    uint4* pv = (uint4*)s.vt;
    for (int i = tid; i < 2048; i += NTH) pv[i] = z;
    if (tid < 224) ((uint4*)(s.bufA + 98 * CH))[tid] = z;
    if (tid < 27) ((uint4*)s.catbits)[tid] = z;
    if (tid >= NTH - (VPAD - VOL)) s.cat[VOL + tid - (NTH - (VPAD - VOL))] = -1;
  }
  __syncthreads();

  // phase 1: LayerNorm into bufA (as xn), one token per 16-lane group + tables
  {
    const int grp = tid >> 4;
    const int l = tid & 15;
    const float4 g0 = *(const float4*)(gamma + l * 8);
    const float4 g1 = *(const float4*)(gamma + l * 8 + 4);
    const float4 be0 = *(const float4*)(beta + l * 8);
    const float4 be1 = *(const float4*)(beta + l * 8 + 4);
    for (int i = grp; i < VOL; i += NTH / 16) {
      int dt = (i >= 49) ? 1 : 0;
      int rem = i - dt * 49;
      int dh = (rem * 37) >> 8;
      int dw = rem - dh * 7;
      int t = nt * 2 + dt, h = nh * 7 + dh, w = nw * 7 + dw;
      int ts = (t + 1) & 15;
      int hs = h + 3; if (hs >= 56) hs -= 56;
      int ws2 = w + 3; if (ws2 >= 56) ws2 -= 56;
      int gi = ((b * 16 + ts) * 56 + hs) * 56 + ws2;
      const float* xp = x + (size_t)gi * CH + l * 8;
      float4 v0 = *(const float4*)(xp);
      float4 v1 = *(const float4*)(xp + 4);
      float sum = v0.x + v0.y + v0.z + v0.w + v1.x + v1.y + v1.z + v1.w;
      float ssq = v0.x * v0.x + v0.y * v0.y + v0.z * v0.z + v0.w * v0.w +
                  v1.x * v1.x + v1.y * v1.y + v1.z * v1.z + v1.w * v1.w;
#pragma unroll
      for (int d = 1; d < 16; d <<= 1) {
        sum += __shfl_xor(sum, d);
        ssq += __shfl_xor(ssq, d);
      }
      float mean = sum * (1.0f / 128.0f);
      float var = ssq * (1.0f / 128.0f) - mean * mean;
      float rstd = rsqrtf(var + 1e-5f);
      uint4 pkv;
      pkv.x = pk2((v0.x - mean) * rstd * g0.x + be0.x, (v0.y - mean) * rstd * g0.y + be0.y);
      pkv.y = pk2((v0.z - mean) * rstd * g0.z + be0.z, (v0.w - mean) * rstd * g0.w + be0.w);
      pkv.z = pk2((v1.x - mean) * rstd * g1.x + be1.x, (v1.y - mean) * rstd * g1.y + be1.y);
      pkv.w = pk2((v1.z - mean) * rstd * g1.z + be1.z, (v1.w - mean) * rstd * g1.w + be1.w);
      ldsWr128(s.bufA, i, l * 8, 256, pkv);
      if (l == 0) {
        int tc = (t < 14) ? 0 : ((t < 15) ? 1 : 2);
        int hc = (h < 49) ? 0 : ((h < 53) ? 1 : 2);
        int wc = (w < 49) ? 0 : ((w < 53) ? 1 : 2);
        int c = tc * 9 + hc * 3 + wc;
        s.cat[i] = c;
        s.gidx[i] = gi;
        atomicOr(&s.catbits[c][i >> 5], 1u << (i & 31));
      }
    }
  }
  __syncthreads();

  // phase 2: load own-row A-frags (xn), barrier, then QKV GEMM.
  // Q (ct 0..7, swapped-operand) -> packed registers qp[8][2];
  // K (ct 8..15, swapped)        -> bufA (overwrites xn);
  // V (ct 16..23, normal)        -> vt as V^T.
  s16x8 xf[4];
#pragma unroll
  for (int ks = 0; ks < 4; ++ks) xf[ks] = ldsRd(s.bufA, itw * 16 + l15, ks * 32 + lg8, 256);
  __syncthreads();   // all xn reads done; bufA may now be overwritten by K

  unsigned qp[8][2];
  {
    const float QSCALE = (float)(0.17677669529663687 * 1.4426950408889634);  // hd^-0.5 * log2e
#pragma unroll
    for (int ct = 0; ct < 24; ++ct) {
      const unsigned short* wf = wfrag + ((size_t)ct * 2048 + (size_t)lane * 8);
      s16x8 wv[4];
#pragma unroll
      for (int ks = 0; ks < 4; ++ks) wv[ks] = *(const s16x8*)(wf + ks * 512);
      f32x4_t acc = {0.f, 0.f, 0.f, 0.f};
      if (ct < 16) {
#pragma unroll
        for (int ks = 0; ks < 4; ++ks)
          acc = __builtin_amdgcn_mfma_f32_16x16x32_bf16(wv[ks], xf[ks], acc, 0, 0, 0);
        if (ct < 8) {
          qp[ct][0] = pk2(acc[0] * QSCALE, acc[1] * QSCALE);
          qp[ct][1] = pk2(acc[2] * QSCALE, acc[3] * QSCALE);
        } else {
          ldsWr64(s.bufA, itw * 16 + l15, (ct - 8) * 16 + lg4, 256,
                  pk2(acc[0], acc[1]), pk2(acc[2], acc[3]));
        }
      } else {
#pragma unroll
        for (int ks = 0; ks < 4; ++ks)
          acc = __builtin_amdgcn_mfma_f32_16x16x32_bf16(xf[ks], wv[ks], acc, 0, 0, 0);
        ldsWr64(s.vt, (ct - 16) * 16 + l15, itw * 16 + lg4, 256,
                pk2(acc[0], acc[1]), pk2(acc[2], acc[3]));
      }
    }
  }
  __syncthreads();

  // phase 3: attention, all 4 heads per wave. S^T = mfma(K, Q, C=mask);
  // lane owns query q = itw*16+l15, keys j = jt*16+lg4+r.
  unsigned oreg[4][4];
  {
    unsigned short* ps = s.pst[itw];
    const int q = itw * 16 + l15;
    int cq = s.cat[q]; if (cq < 0) cq = 0;
    const uint4 mwv = *(const uint4*)&s.catbits[cq][0];
    f32x4_t cm[7];
#pragma unroll
    for (int jt = 0; jt < 7; ++jt) {
      unsigned mword = ((jt >> 1) == 0) ? mwv.x : ((jt >> 1) == 1) ? mwv.y
                      : ((jt >> 1) == 2) ? mwv.z : mwv.w;
#pragma unroll
      for (int r = 0; r < 4; ++r)
        cm[jt][r] = ((mword >> ((jt & 1) * 16 + lg4 + r)) & 1u) ? 0.f : MASKNEG;
    }
    const int srcA = ((lg & 1) * 2) * 16 + l15;
    const int srcB = ((lg & 1) * 2 + 1) * 16 + l15;
    const bool hiT = (lg >> 1) != 0;
#pragma unroll
    for (int hh = 0; hh < 4; ++hh) {
      // qa fragment from Q registers via cross-lg shuffles (same l15 column)
      unsigned a0 = __shfl(qp[2 * hh][0], srcA), b0 = __shfl(qp[2 * hh + 1][0], srcA);
      unsigned a1 = __shfl(qp[2 * hh][1], srcA), b1 = __shfl(qp[2 * hh + 1][1], srcA);
      unsigned a2 = __shfl(qp[2 * hh][0], srcB), b2 = __shfl(qp[2 * hh + 1][0], srcB);
      unsigned a3 = __shfl(qp[2 * hh][1], srcB), b3 = __shfl(qp[2 * hh + 1][1], srcB);
      s16x8 qa = u4cast(hiT ? b0 : a0, hiT ? b1 : a1, hiT ? b2 : a2, hiT ? b3 : a3);
      f32x4_t sc[7];
#pragma unroll
      for (int jt = 0; jt < 7; ++jt) {
        s16x8 kb = ldsRd(s.bufA, jt * 16 + l15, hh * 32 + lg8, 256);
        sc[jt] = __builtin_amdgcn_mfma_f32_16x16x32_bf16(kb, qa, cm[jt], 0, 0, 0);
      }
      // softmax over j (log2 domain; scale folded into Q)
      float m = sc[0][0];
#pragma unroll
      for (int jt = 0; jt < 7; ++jt)
#pragma unroll
        for (int r = 0; r < 4; ++r) m = fmaxf(m, sc[jt][r]);
      m = fmaxf(m, __shfl_xor(m, 16));
      m = fmaxf(m, __shfl_xor(m, 32));
      float ssum = 0.f;
#pragma unroll
      for (int jt = 0; jt < 7; ++jt)
#pragma unroll
        for (int r = 0; r < 4; ++r) {
          float p = exp2f(sc[jt][r] - m);
          sc[jt][r] = p;
          ssum += p;
        }
      ssum += __shfl_xor(ssum, 16);
      ssum += __shfl_xor(ssum, 32);
      float rinv = 1.0f / ssum;
      // PV per 32-key chunk via per-wave staging tile (P unnormalized)
      f32x4_t o0 = {0.f, 0.f, 0.f, 0.f}, o1 = {0.f, 0.f, 0.f, 0.f};
#pragma unroll
      for (int ks = 0; ks < 4; ++ks) {
        const int jtA = 2 * ks, jtB = 2 * ks + 1;
        ldsWr64(ps, l15, lg4, 64, pk2(sc[jtA][0], sc[jtA][1]), pk2(sc[jtA][2], sc[jtA][3]));
        unsigned pb0 = 0, pb1 = 0;
        if (jtB < 7) {
          pb0 = pk2(sc[jtB][0], sc[jtB][1]);
          pb1 = pk2(sc[jtB][2], sc[jtB][3]);
        }
        ldsWr64(ps, l15, 16 + lg4, 64, pb0, pb1);
        asm volatile("" ::: "memory");  // order pst write (u64*) vs read (short8*)
        s16x8 pa = ldsRd(ps, l15, lg8, 64);
        s16x8 v0 = ldsRd(s.vt, hh * 32 + l15, ks * 32 + lg8, 256);
        s16x8 v1 = ldsRd(s.vt, hh * 32 + 16 + l15, ks * 32 + lg8, 256);
        o0 = __builtin_amdgcn_mfma_f32_16x16x32_bf16(v0, pa, o0, 0, 0, 0);
        o1 = __builtin_amdgcn_mfma_f32_16x16x32_bf16(v1, pa, o1, 0, 0, 0);
      }
      oreg[hh][0] = pk2(o0[0] * rinv, o0[1] * rinv);
      oreg[hh][1] = pk2(o0[2] * rinv, o0[3] * rinv);
      oreg[hh][2] = pk2(o1[0] * rinv, o1[1] * rinv);
      oreg[hh][3] = pk2(o1[2] * rinv, o1[3] * rinv);
    }
  }
  __syncthreads();   // all K (bufA) / V reads done block-wide

  // write O over bufA (lane holds 4+4 consecutive d per head for its q)
  {
    const int q = itw * 16 + l15;
#pragma unroll
    for (int hh = 0; hh < 4; ++hh) {
      ldsWr64(s.bufA, q, hh * 32 + lg4, 256, oreg[hh][0], oreg[hh][1]);
      ldsWr64(s.bufA, q, hh * 32 + 16 + lg4, 256, oreg[hh][2], oreg[hh][3]);
    }
  }
  __syncthreads();

  // phase 4: proj GEMM (swapped; bias via C-operand) + float4 store
  {
    const unsigned short* wp = wfrag + 49152;
    s16x8 of[4];
#pragma unroll
    for (int ks = 0; ks < 4; ++ks) of[ks] = ldsRd(s.bufA, itw * 16 + l15, ks * 32 + lg8, 256);
    const int row = itw * 16 + l15;
    const bool valid = row < VOL;
    const size_t gbase = valid ? (size_t)s.gidx[row] * CH : 0;
#pragma unroll
    for (int ct = 0; ct < 8; ++ct) {
      const unsigned short* wf = wp + ((size_t)ct * 2048 + (size_t)lane * 8);
      float4 b4 = *(const float4*)(bproj + ct * 16 + lg4);
      f32x4_t acc = {b4.x, b4.y, b4.z, b4.w};
#pragma unroll
      for (int ks = 0; ks < 4; ++ks) {
        s16x8 wv = *(const s16x8*)(wf + ks * 512);
        acc = __builtin_amdgcn_mfma_f32_16x16x32_bf16(wv, of[ks], acc, 0, 0, 0);
      }
      if (valid) {
        float4 res;
        res.x = acc[0]; res.y = acc[1]; res.z = acc[2]; res.w = acc[3];
        *(float4*)(out + gbase + ct * 16 + lg4) = res;
      }
    }
  }
}

extern "C" void kernel_launch(void* const* d_in, const int* in_sizes, int n_in,
                              void* d_out, int out_size, void* d_ws, size_t ws_size,
                              hipStream_t stream) {
  const float* x = (const float*)d_in[0];
  const float* gamma = (const float*)d_in[1];
  const float* beta = (const float*)d_in[2];
  const float* wqkv = (const float*)d_in[3];
  const float* wproj = (const float*)d_in[4];
  const float* bproj = (const float*)d_in[5];
  float* out = (float*)d_out;
  unsigned short* wsf = (unsigned short*)d_ws;
  (void)in_sizes; (void)n_in; (void)out_size; (void)ws_size;

  prepack_weights<<<128, 64, 0, stream>>>(wqkv, wproj, wsf);
  fused_cuboid_attn<<<1024, NTH, 0, stream>>>(x, gamma, beta, bproj, wsf, out);
}

// Round 8
// 74.739 us; speedup vs baseline: 1.8698x; 1.0621x over previous
//
#include <hip/hip_runtime.h>

typedef short s16x8 __attribute__((ext_vector_type(8)));
typedef float f32x4_t __attribute__((ext_vector_type(4)));

#define VOL 98
#define VPAD 112
#define CH 128
#define NWV 7
#define NTH (NWV * 64)
#define MASKNEG -1e9f

struct Smem {
  unsigned short bufA[VPAD * CH];   // 28672 B: xn (LN out) -> K -> O; stride 256B swz
  unsigned short vt[CH * CH];       // 32768 B: V^T [d][token]; stride 256B swz
  unsigned short pst[NWV][512];     // 7168 B: per-wave P staging [q16][j32]; stride 64B swz
  unsigned int catbits[27][4];      // 432 B: bit j of catbits[c] => token j has category c
  int cat[VPAD];
  int gidx[VPAD];
};

__device__ __forceinline__ unsigned short f2bf(float f) {
  unsigned int u = __float_as_uint(f);
  unsigned int r = u + 0x7FFFu + ((u >> 16) & 1u);
  return (unsigned short)(r >> 16);
}
// packed f32x2 -> bf16x2, round-half-up + v_perm_b32 pack (3 VALU, no inline
// asm). NOTE: the inline-asm v_cvt_pk_bf16_f32 variant NaN'd in R3/R4/R7 and
// is banned; manual path is the fallback (R1/R2/R5/R6-proven).
__device__ __forceinline__ unsigned int pk2(float a, float b) {
#if __has_builtin(__builtin_amdgcn_perm)
  return __builtin_amdgcn_perm(__float_as_uint(b) + 0x8000u,
                               __float_as_uint(a) + 0x8000u,
                               0x07060302u);
#else
  return (unsigned int)f2bf(a) | ((unsigned int)f2bf(b) << 16);
#endif
}
__device__ __forceinline__ int swz(int row, int colEl, int strideB) {
  return (row * strideB + colEl * 2) ^ ((row & 7) << 4);
}
__device__ __forceinline__ s16x8 ldsRd(const unsigned short* buf, int row, int colEl, int strideB) {
  return *(const s16x8*)((const char*)buf + swz(row, colEl, strideB));
}
__device__ __forceinline__ void ldsWr64(unsigned short* buf, int row, int colEl, int strideB,
                                        unsigned int lo, unsigned int hi) {
  unsigned long long v = (unsigned long long)lo | ((unsigned long long)hi << 32);
  *(unsigned long long*)((char*)buf + swz(row, colEl, strideB)) = v;
}
__device__ __forceinline__ void ldsWr128(unsigned short* buf, int row, int colEl, int strideB, uint4 v) {
  *(uint4*)((char*)buf + swz(row, colEl, strideB)) = v;
}
__device__ __forceinline__ s16x8 u4cast(unsigned a, unsigned b, unsigned c, unsigned d) {
  union { uint4 u; s16x8 v; } cv;
  cv.u = make_uint4(a, b, c, d);
  return cv.v;
}

// ---------------- weight prepack: fp32 -> bf16 fragments (exact RNE) ----------------
__global__ void prepack_weights(const float* __restrict__ wqkv,
                                const float* __restrict__ wproj,
                                unsigned short* __restrict__ dst) {
  int lane = threadIdx.x;
  int blk = blockIdx.x;
  if (blk < 96) {
    int ct = blk >> 2, ks = blk & 3;
    int r0 = ks * 32 + ((lane >> 4) << 3);
    int col = ct * 16 + (lane & 15);
    unsigned short* d = dst + (((size_t)(ct * 4 + ks) * 64 + lane) * 8);
#pragma unroll
    for (int j = 0; j < 8; ++j) d[j] = f2bf(wqkv[(size_t)(r0 + j) * 384 + col]);
  } else {
    int bb = blk - 96;
    int ct = bb >> 2, ks = bb & 3;
    int r0 = ks * 32 + ((lane >> 4) << 3);
    int col = ct * 16 + (lane & 15);
    unsigned short* d = dst + 49152 + (((size_t)(ct * 4 + ks) * 64 + lane) * 8);
#pragma unroll
    for (int j = 0; j < 8; ++j) d[j] = f2bf(wproj[(size_t)(r0 + j) * 128 + col]);
  }
}

// ---------------- fused kernel: one block per cuboid, 7 waves ----------------
__global__ __launch_bounds__(NTH, 4) void fused_cuboid_attn(
    const float* __restrict__ x, const float* __restrict__ gamma,
    const float* __restrict__ beta, const float* __restrict__ bproj,
    const unsigned short* __restrict__ wfrag, float* __restrict__ out) {
  __shared__ Smem s;
  const int tid = threadIdx.x;
  const int lane = tid & 63;
  const int itw = tid >> 6;          // wave id == row-tile id (0..6)
  const int l15 = lane & 15;
  const int lg = lane >> 4;
  const int lg4 = lg * 4;
  const int lg8 = lg * 8;
  const int bid = blockIdx.x;
  const int b = bid >> 9;
  const int n = bid & 511;
  const int nt = n >> 6, nh = (n >> 3) & 7, nw = n & 7;

  // phase 1a: issue ALL x loads for this thread's LN tokens up front
  // (independent loads in flight; latency hidden under zeroing + index math)
  const int grp = tid >> 4;
  const int l = tid & 15;
  float4 xv[4][2];
  int giv[4], catv[4];
#pragma unroll
  for (int it2 = 0; it2 < 4; ++it2) {
    int i = grp + it2 * 28;
    if (i < VOL) {
      int dt = (i >= 49) ? 1 : 0;
      int rem = i - dt * 49;
      int dh = (rem * 37) >> 8;
      int dw = rem - dh * 7;
      int t = nt * 2 + dt, h = nh * 7 + dh, w = nw * 7 + dw;
      int ts = (t + 1) & 15;
      int hs = h + 3; if (hs >= 56) hs -= 56;
      int ws2 = w + 3; if (ws2 >= 56) ws2 -= 56;
      int gi = ((b * 16 + ts) * 56 + hs) * 56 + ws2;
      const float* xp = x + (size_t)gi * CH + l * 8;
      xv[it2][0] = *(const float4*)(xp);
      xv[it2][1] = *(const float4*)(xp + 4);
      giv[it2] = gi;
      int tc = (t < 14) ? 0 : ((t < 15) ? 1 : 2);
      int hc = (h < 49) ? 0 : ((h < 53) ? 1 : 2);
      int wc = (w < 49) ? 0 : ((w < 53) ? 1 : 2);
      catv[it2] = tc * 9 + hc * 3 + wc;
    }
  }

  // phase 0: zero vt (fully: swizzle scatters unwritten token-cols 112..127),
  // bufA pad rows 98..111 (-> zero K pads via GEMM), catbits, cat pads.
  {
    uint4 z = make_uint4(0, 0, 0, 0);
    uint4* pv = (uint4*)s.vt;
    for (int i = tid; i < 2048; i += NTH) pv[i] = z;
    if (tid < 224) ((uint4*)(s.bufA + 98 * CH))[tid] = z;
    if (tid < 27) ((uint4*)s.catbits)[tid] = z;
    if (tid >= NTH - (VPAD - VOL)) s.cat[VOL + tid - (NTH - (VPAD - VOL))] = -1;
  }
  __syncthreads();

  // phase 1b: LayerNorm into bufA (as xn), one token per 16-lane group + tables
  {
    const float4 g0 = *(const float4*)(gamma + l * 8);
    const float4 g1 = *(const float4*)(gamma + l * 8 + 4);
    const float4 be0 = *(const float4*)(beta + l * 8);
    const float4 be1 = *(const float4*)(beta + l * 8 + 4);
#pragma unroll
    for (int it2 = 0; it2 < 4; ++it2) {
      int i = grp + it2 * 28;
      if (i < VOL) {
        float4 v0 = xv[it2][0];
        float4 v1 = xv[it2][1];
        float sum = v0.x + v0.y + v0.z + v0.w + v1.x + v1.y + v1.z + v1.w;
        float ssq = v0.x * v0.x + v0.y * v0.y + v0.z * v0.z + v0.w * v0.w +
                    v1.x * v1.x + v1.y * v1.y + v1.z * v1.z + v1.w * v1.w;
#pragma unroll
        for (int d = 1; d < 16; d <<= 1) {
          sum += __shfl_xor(sum, d);
          ssq += __shfl_xor(ssq, d);
        }
        float mean = sum * (1.0f / 128.0f);
        float var = ssq * (1.0f / 128.0f) - mean * mean;
        float rstd = rsqrtf(var + 1e-5f);
        uint4 pkv;
        pkv.x = pk2((v0.x - mean) * rstd * g0.x + be0.x, (v0.y - mean) * rstd * g0.y + be0.y);
        pkv.y = pk2((v0.z - mean) * rstd * g0.z + be0.z, (v0.w - mean) * rstd * g0.w + be0.w);
        pkv.z = pk2((v1.x - mean) * rstd * g1.x + be1.x, (v1.y - mean) * rstd * g1.y + be1.y);
        pkv.w = pk2((v1.z - mean) * rstd * g1.z + be1.z, (v1.w - mean) * rstd * g1.w + be1.w);
        ldsWr128(s.bufA, i, l * 8, 256, pkv);
        if (l == 0) {
          s.cat[i] = catv[it2];
          s.gidx[i] = giv[it2];
          atomicOr(&s.catbits[catv[it2]][i >> 5], 1u << (i & 31));
        }
      }
    }
  }
  __syncthreads();

  // phase 2: load own-row A-frags (xn), barrier, then QKV GEMM.
  // Q (ct 0..7, swapped-operand) -> packed registers qp[8][2];
  // K (ct 8..15, swapped)        -> bufA (overwrites xn);
  // V (ct 16..23, normal)        -> vt as V^T.
  s16x8 xf[4];
#pragma unroll
  for (int ks = 0; ks < 4; ++ks) xf[ks] = ldsRd(s.bufA, itw * 16 + l15, ks * 32 + lg8, 256);
  __syncthreads();   // all xn reads done; bufA may now be overwritten by K

  unsigned qp[8][2];
  {
    const float QSCALE = (float)(0.17677669529663687 * 1.4426950408889634);  // hd^-0.5 * log2e
#pragma unroll
    for (int ct = 0; ct < 24; ++ct) {
      const unsigned short* wf = wfrag + ((size_t)ct * 2048 + (size_t)lane * 8);
      s16x8 wv[4];
#pragma unroll
      for (int ks = 0; ks < 4; ++ks) wv[ks] = *(const s16x8*)(wf + ks * 512);
      f32x4_t acc = {0.f, 0.f, 0.f, 0.f};
      if (ct < 16) {
#pragma unroll
        for (int ks = 0; ks < 4; ++ks)
          acc = __builtin_amdgcn_mfma_f32_16x16x32_bf16(wv[ks], xf[ks], acc, 0, 0, 0);
        if (ct < 8) {
          qp[ct][0] = pk2(acc[0] * QSCALE, acc[1] * QSCALE);
          qp[ct][1] = pk2(acc[2] * QSCALE, acc[3] * QSCALE);
        } else {
          ldsWr64(s.bufA, itw * 16 + l15, (ct - 8) * 16 + lg4, 256,
                  pk2(acc[0], acc[1]), pk2(acc[2], acc[3]));
        }
      } else {
#pragma unroll
        for (int ks = 0; ks < 4; ++ks)
          acc = __builtin_amdgcn_mfma_f32_16x16x32_bf16(xf[ks], wv[ks], acc, 0, 0, 0);
        ldsWr64(s.vt, (ct - 16) * 16 + l15, itw * 16 + lg4, 256,
                pk2(acc[0], acc[1]), pk2(acc[2], acc[3]));
      }
    }
  }
  __syncthreads();

  // phase 3: attention, all 4 heads per wave. S^T = mfma(K, Q, C=mask);
  // lane owns query q = itw*16+l15, keys j = jt*16+lg4+r.
  unsigned oreg[4][4];
  {
    unsigned short* ps = s.pst[itw];
    const int q = itw * 16 + l15;
    int cq = s.cat[q]; if (cq < 0) cq = 0;
    const uint4 mwv = *(const uint4*)&s.catbits[cq][0];
    f32x4_t cm[7];
#pragma unroll
    for (int jt = 0; jt < 7; ++jt) {
      unsigned mword = ((jt >> 1) == 0) ? mwv.x : ((jt >> 1) == 1) ? mwv.y
                      : ((jt >> 1) == 2) ? mwv.z : mwv.w;
#pragma unroll
      for (int r = 0; r < 4; ++r)
        cm[jt][r] = ((mword >> ((jt & 1) * 16 + lg4 + r)) & 1u) ? 0.f : MASKNEG;
    }
    const int srcA = ((lg & 1) * 2) * 16 + l15;
    const int srcB = ((lg & 1) * 2 + 1) * 16 + l15;
    const bool hiT = (lg >> 1) != 0;
#pragma unroll
    for (int hh = 0; hh < 4; ++hh) {
      // qa fragment from Q registers via cross-lg shuffles (same l15 column)
      unsigned a0 = __shfl(qp[2 * hh][0], srcA), b0 = __shfl(qp[2 * hh + 1][0], srcA);
      unsigned a1 = __shfl(qp[2 * hh][1], srcA), b1 = __shfl(qp[2 * hh + 1][1], srcA);
      unsigned a2 = __shfl(qp[2 * hh][0], srcB), b2 = __shfl(qp[2 * hh + 1][0], srcB);
      unsigned a3 = __shfl(qp[2 * hh][1], srcB), b3 = __shfl(qp[2 * hh + 1][1], srcB);
      s16x8 qa = u4cast(hiT ? b0 : a0, hiT ? b1 : a1, hiT ? b2 : a2, hiT ? b3 : a3);
      f32x4_t sc[7];
#pragma unroll
      for (int jt = 0; jt < 7; ++jt) {
        s16x8 kb = ldsRd(s.bufA, jt * 16 + l15, hh * 32 + lg8, 256);
        sc[jt] = __builtin_amdgcn_mfma_f32_16x16x32_bf16(kb, qa, cm[jt], 0, 0, 0);
      }
      // softmax over j (log2 domain; scale folded into Q); 4 independent chains
      float m0 = sc[0][0], m1 = sc[0][1], m2 = sc[0][2], m3 = sc[0][3];
#pragma unroll
      for (int jt = 1; jt < 7; ++jt) {
        m0 = fmaxf(m0, sc[jt][0]);
        m1 = fmaxf(m1, sc[jt][1]);
        m2 = fmaxf(m2, sc[jt][2]);
        m3 = fmaxf(m3, sc[jt][3]);
      }
      float m = fmaxf(fmaxf(m0, m1), fmaxf(m2, m3));
      m = fmaxf(m, __shfl_xor(m, 16));
      m = fmaxf(m, __shfl_xor(m, 32));
      float s0 = 0.f, s1 = 0.f, s2 = 0.f, s3 = 0.f;
#pragma unroll
      for (int jt = 0; jt < 7; ++jt) {
        float p0 = exp2f(sc[jt][0] - m);
        float p1 = exp2f(sc[jt][1] - m);
        float p2 = exp2f(sc[jt][2] - m);
        float p3 = exp2f(sc[jt][3] - m);
        sc[jt][0] = p0; sc[jt][1] = p1; sc[jt][2] = p2; sc[jt][3] = p3;
        s0 += p0; s1 += p1; s2 += p2; s3 += p3;
      }
      float ssum = (s0 + s1) + (s2 + s3);
      ssum += __shfl_xor(ssum, 16);
      ssum += __shfl_xor(ssum, 32);
      float rinv = 1.0f / ssum;
      // PV per 32-key chunk via per-wave staging tile (P unnormalized)
      f32x4_t o0 = {0.f, 0.f, 0.f, 0.f}, o1 = {0.f, 0.f, 0.f, 0.f};
#pragma unroll
      for (int ks = 0; ks < 4; ++ks) {
        const int jtA = 2 * ks, jtB = 2 * ks + 1;
        ldsWr64(ps, l15, lg4, 64, pk2(sc[jtA][0], sc[jtA][1]), pk2(sc[jtA][2], sc[jtA][3]));
        unsigned pb0 = 0, pb1 = 0;
        if (jtB < 7) {
          pb0 = pk2(sc[jtB][0], sc[jtB][1]);
          pb1 = pk2(sc[jtB][2], sc[jtB][3]);
        }
        ldsWr64(ps, l15, 16 + lg4, 64, pb0, pb1);
        asm volatile("" ::: "memory");  // order pst write (u64*) vs read (short8*)
        s16x8 pa = ldsRd(ps, l15, lg8, 64);
        s16x8 v0 = ldsRd(s.vt, hh * 32 + l15, ks * 32 + lg8, 256);
        s16x8 v1 = ldsRd(s.vt, hh * 32 + 16 + l15, ks * 32 + lg8, 256);
        o0 = __builtin_amdgcn_mfma_f32_16x16x32_bf16(v0, pa, o0, 0, 0, 0);
        o1 = __builtin_amdgcn_mfma_f32_16x16x32_bf16(v1, pa, o1, 0, 0, 0);
      }
      oreg[hh][0] = pk2(o0[0] * rinv, o0[1] * rinv);
      oreg[hh][1] = pk2(o0[2] * rinv, o0[3] * rinv);
      oreg[hh][2] = pk2(o1[0] * rinv, o1[1] * rinv);
      oreg[hh][3] = pk2(o1[2] * rinv, o1[3] * rinv);
    }
  }
  __syncthreads();   // all K (bufA) / V reads done block-wide

  // write O over bufA (lane holds 4+4 consecutive d per head for its q)
  {
    const int q = itw * 16 + l15;
#pragma unroll
    for (int hh = 0; hh < 4; ++hh) {
      ldsWr64(s.bufA, q, hh * 32 + lg4, 256, oreg[hh][0], oreg[hh][1]);
      ldsWr64(s.bufA, q, hh * 32 + 16 + lg4, 256, oreg[hh][2], oreg[hh][3]);
    }
  }
  __syncthreads();

  // phase 4: proj GEMM (swapped; bias via C-operand) + float4 store
  {
    const unsigned short* wp = wfrag + 49152;
    s16x8 of[4];
#pragma unroll
    for (int ks = 0; ks < 4; ++ks) of[ks] = ldsRd(s.bufA, itw * 16 + l15, ks * 32 + lg8, 256);
    const int row = itw * 16 + l15;
    const bool valid = row < VOL;
    const size_t gbase = valid ? (size_t)s.gidx[row] * CH : 0;
#pragma unroll
    for (int ct = 0; ct < 8; ++ct) {
      const unsigned short* wf = wp + ((size_t)ct * 2048 + (size_t)lane * 8);
      float4 b4 = *(const float4*)(bproj + ct * 16 + lg4);
      f32x4_t acc = {b4.x, b4.y, b4.z, b4.w};
#pragma unroll
      for (int ks = 0; ks < 4; ++ks) {
        s16x8 wv = *(const s16x8*)(wf + ks * 512);
        acc = __builtin_amdgcn_mfma_f32_16x16x32_bf16(wv, of[ks], acc, 0, 0, 0);
      }
      if (valid) {
        float4 res;
        res.x = acc[0]; res.y = acc[1]; res.z = acc[2]; res.w = acc[3];
        *(float4*)(out + gbase + ct * 16 + lg4) = res;
      }
    }
  }
}

extern "C" void kernel_launch(void* const* d_in, const int* in_sizes, int n_in,
                              void* d_out, int out_size, void* d_ws, size_t ws_size,
                              hipStream_t stream) {
  const float* x = (const float*)d_in[0];
  const float* gamma = (const float*)d_in[1];
  const float* beta = (const float*)d_in[2];
  const float* wqkv = (const float*)d_in[3];
  const float* wproj = (const float*)d_in[4];
  const float* bproj = (const float*)d_in[5];
  float* out = (float*)d_out;
  unsigned short* wsf = (unsigned short*)d_ws;
  (void)in_sizes; (void)n_in; (void)out_size; (void)ws_size;

  prepack_weights<<<128, 64, 0, stream>>>(wqkv, wproj, wsf);
  fused_cuboid_attn<<<1024, NTH, 0, stream>>>(x, gamma, beta, bproj, wsf, out);
}